// Round 8
// baseline (279.602 us; speedup 1.0000x reference)
//
#include <hip/hip_runtime.h>

typedef int   i32x8 __attribute__((ext_vector_type(8)));
typedef float f32x4 __attribute__((ext_vector_type(4)));

#define B_   8
#define N_   4096
#define D_   256

// fp8 fragment-major blob layout:
//   blob[g16][kt][h] = 1 KB chunk; lane l's 16 bytes at +l*16 hold
//   P[g16*16 + (l&15)][k = kt*128 + (l>>4)*32 + h*16 .. +16]  (e4m3)
// i.e. per-lane k-contiguous 32-byte operand rows for mfma_scale 16x16x128.

__device__ __forceinline__ void gl_lds16(const void* g, void* l) {
  __builtin_amdgcn_global_load_lds(
      (const __attribute__((address_space(1))) unsigned int*)g,
      (__attribute__((address_space(3))) unsigned int*)l, 16, 0, 0);
}

// sum of squares of the 4 e4m3 bytes in w (selector must be a literal)
__device__ __forceinline__ float sq8(unsigned w) {
  float f0 = __builtin_amdgcn_cvt_f32_fp8(w, 0);
  float f1 = __builtin_amdgcn_cvt_f32_fp8(w, 1);
  float f2 = __builtin_amdgcn_cvt_f32_fp8(w, 2);
  float f3 = __builtin_amdgcn_cvt_f32_fp8(w, 3);
  return f0 * f0 + f1 * f1 + f2 * f2 + f3 * f3;
}

// One wave per 16-row group: fp32 -> fp8 e4m3 convert (coalesced 1 KB float4
// reads), in-wave LDS transpose to fragment-major, norms of DEQUANTIZED
// values accumulated during readback (2 shuffles total), min-init.
__global__ __launch_bounds__(256) void prep_kernel(
    const float* __restrict__ x, const float* __restrict__ y,
    unsigned char* __restrict__ Xf, unsigned char* __restrict__ Yf,
    float* __restrict__ xx, float* __restrict__ yy,
    unsigned* __restrict__ rowmin, unsigned* __restrict__ colmin,
    float* __restrict__ out)
{
  __shared__ unsigned char T[4][16 * 272];   // 16 rows x 256B fp8 (+16 pad)
  if (blockIdx.x == 0 && threadIdx.x == 0) out[0] = 0.f;

  const int wv = threadIdx.x >> 6, lane = threadIdx.x & 63;
  const int wid = (blockIdx.x << 2) + wv;          // 0..4095

  const float* src; unsigned char* dst; float* nrm; unsigned* mn; int g;
  if (wid < 2048) { g = wid;        src = x; dst = Xf; nrm = xx; mn = rowmin; }
  else            { g = wid - 2048; src = y; dst = Yf; nrm = yy; mn = colmin; }

  unsigned char* tw = T[wv];
  const float* rp = src + (size_t)g * 16 * D_;
#pragma unroll
  for (int r = 0; r < 16; ++r) {
    float4 v = *(const float4*)(rp + r * D_ + lane * 4);   // 1 KB contiguous
    unsigned u = __builtin_amdgcn_cvt_pk_fp8_f32(v.x, v.y, 0, 0);
    u = __builtin_amdgcn_cvt_pk_fp8_f32(v.z, v.w, u, 1);   // bytes = x,y,z,w
    *(unsigned*)(tw + r * 272 + lane * 4) = u;
  }
  __syncthreads();

  // fragment-order readback: row = lane&15, k-base = (lane>>4)*32
  float s = 0.f;
  const int row = lane & 15, ko = (lane >> 4) * 32;
#pragma unroll
  for (int kt = 0; kt < 2; ++kt)
#pragma unroll
    for (int h = 0; h < 2; ++h) {
      uint4 c = *(const uint4*)(tw + row * 272 + kt * 128 + ko + h * 16);
      s += sq8(c.x) + sq8(c.y) + sq8(c.z) + sq8(c.w);
      *(uint4*)(dst + ((((size_t)g * 2 + kt) * 2 + h) << 10) + lane * 16) = c;
    }
  s += __shfl_xor(s, 16, 64);   // fold quads: row (lane&15)'s full norm
  s += __shfl_xor(s, 32, 64);
  if      (lane < 16) nrm[g * 16 + lane] = s;
  else if (lane < 32) mn[g * 16 + lane - 16] = 0x7f800000u;   // +inf
}

// MX-fp8 chamfer GEMM (mfma_scale_f32_16x16x128_f8f6f4, scales = 1.0).
// Block: 256 rows x 512 cols; 4 waves x 64 rows; af[4][2] (v8i32) in regs;
// B staged per 32-col tile (8 KB), double-buffered, one barrier per tile.
// Grid 1024 = 4 blocks/CU (vs round-7's 2): one block's barrier drain
// overlaps another's MFMA/VALU phase (m114 co-scheduling).
__global__ __launch_bounds__(256, 4) void chamfer_gemm(
    const unsigned char* __restrict__ Xf, const unsigned char* __restrict__ Yf,
    const float* __restrict__ xx, const float* __restrict__ yy,
    unsigned* __restrict__ rowmin, unsigned* __restrict__ colmin)
{
  __shared__ __align__(16) unsigned char S[2][8192];   // B double-buffer
  __shared__ unsigned cmin_s[512];                     // col-min table

  const int bid = blockIdx.x;
  const int b   = bid & 7;                   // batch == XCD (L2 locality)
  const int rt  = (bid >> 3) & 15;           // 16 row-tiles of 256
  const int cq  = bid >> 7;                  // 0..7 col-eighths of 512
  const int n0  = rt * 256;
  const int m0  = cq * 512;

  const int t = threadIdx.x, lane = t & 63, wave = t >> 6;
  const int quad = lane >> 4, lcol = lane & 15;

#pragma unroll
  for (int i = 0; i < 2; ++i) cmin_s[t + i * 256] = 0x7f800000u;

  // ---- A fragments -> registers (coalesced dwordx4 from fragment blob) ----
  i32x8 af[4][2];
#pragma unroll
  for (int i = 0; i < 4; ++i) {
    const size_t g = (size_t)(b * 256 + rt * 16 + wave * 4 + i);
#pragma unroll
    for (int kt = 0; kt < 2; ++kt) {
      const uint4* p = (const uint4*)(Xf + ((g * 2 + kt) << 11));
      uint4 lo = p[lane];        // h=0
      uint4 hi = p[64 + lane];   // h=1
      i32x8 a;
      a[0] = lo.x; a[1] = lo.y; a[2] = lo.z; a[3] = lo.w;
      a[4] = hi.x; a[5] = hi.y; a[6] = hi.z; a[7] = hi.w;
      af[i][kt] = a;
    }
  }

  float xv[4][4], rmin[4][4];
  const float* xxp = xx + b * N_ + n0 + wave * 64;
#pragma unroll
  for (int i = 0; i < 4; ++i)
#pragma unroll
    for (int r = 0; r < 4; ++r) {
      xv[i][r] = xxp[i * 16 + quad * 4 + r];
      rmin[i][r] = 1e30f;
    }

  __syncthreads();   // cmin_s init visible

  // B staging: LDS chunk cd = kt*4 + h*2 + j at cd*1024; slot s = t + h2*256
  // -> cd = s>>6 (wave-uniform), lane slot = s&63. Source chunk is a
  // contiguous 1 KB of the fragment blob -> perfectly coalesced.
  const unsigned char* Ybase = Yf + ((size_t)(b * 256 + cq * 32) << 12);
  const float* yyp = yy + b * N_ + m0;

#define STAGE_B(ct_, buf_)                                                    \
  {                                                                           \
    const unsigned char* Ysrc = Ybase + ((size_t)(ct_) << 13);  /* 2 g16 */   \
    _Pragma("unroll")                                                         \
    for (int h2 = 0; h2 < 2; ++h2) {                                          \
      int s  = t + h2 * 256;                                                  \
      int cd = s >> 6, ln = s & 63;                                           \
      int kt = cd >> 2, hh = (cd >> 1) & 1, jj = cd & 1;                      \
      gl_lds16(Ysrc + jj * 4096 + kt * 2048 + hh * 1024 + ln * 16,            \
               (buf_) + s * 16);                                              \
    }                                                                         \
  }

  STAGE_B(0, S[0]);   // prefetch first tile

  for (int ct = 0; ct < 16; ++ct) {
    __syncthreads();                       // drains B(ct) prefetch
    const unsigned char* curb = S[ct & 1];
    if (ct + 1 < 16) STAGE_B(ct + 1, S[(ct + 1) & 1]);

    float yv0 = yyp[ct * 32 + lcol];
    float yv1 = yyp[ct * 32 + 16 + lcol];

    // B fragments: bq[j][kt] from chunks (kt, h, j)
    i32x8 bq[2][2];
#pragma unroll
    for (int j = 0; j < 2; ++j)
#pragma unroll
      for (int kt = 0; kt < 2; ++kt) {
        uint4 lo = *(const uint4*)(curb + (kt * 4 + 0 + j) * 1024 + lane * 16);
        uint4 hi = *(const uint4*)(curb + (kt * 4 + 2 + j) * 1024 + lane * 16);
        i32x8 v;
        v[0] = lo.x; v[1] = lo.y; v[2] = lo.z; v[3] = lo.w;
        v[4] = hi.x; v[5] = hi.y; v[6] = hi.z; v[7] = hi.w;
        bq[j][kt] = v;
      }

    f32x4 acc[4][2] = {};
#pragma unroll
    for (int kt = 0; kt < 2; ++kt)
#pragma unroll
      for (int i = 0; i < 4; ++i)
#pragma unroll
        for (int j = 0; j < 2; ++j)
          acc[i][j] = __builtin_amdgcn_mfma_scale_f32_16x16x128_f8f6f4(
              af[i][kt], bq[j][kt], acc[i][j],
              0, 0,        // cbsz = A fmt e4m3, blgp = B fmt e4m3
              0, 127,      // scale A: opsel 0, e8m0 127 = 1.0
              0, 127);     // scale B

    // ---- epilogue: C/D row = i*16 + quad*4 + r, col = j*16 + lcol ----
#pragma unroll
    for (int j = 0; j < 2; ++j) {
      float yv = j ? yv1 : yv0;
      float cm = 1e30f;
#pragma unroll
      for (int i = 0; i < 4; ++i)
#pragma unroll
        for (int r = 0; r < 4; ++r) {
          float a = acc[i][j][r];
          rmin[i][r] = fminf(rmin[i][r], __builtin_fmaf(-2.0f, a, yv));
          cm         = fminf(cm,         __builtin_fmaf(-2.0f, a, xv[i][r]));
        }
      cm = fminf(cm, __shfl_xor(cm, 16, 64));
      cm = fminf(cm, __shfl_xor(cm, 32, 64));
      if (quad == 0)
        atomicMin(&cmin_s[ct * 32 + j * 16 + lcol], __float_as_uint(cm + yv));
    }
  }

  // rowmin: one global atomic set per block (64 rows/wave)
#pragma unroll
  for (int i = 0; i < 4; ++i)
#pragma unroll
    for (int r = 0; r < 4; ++r) {
      float v = xv[i][r] + rmin[i][r];
#pragma unroll
      for (int m = 1; m < 16; m <<= 1) v = fminf(v, __shfl_xor(v, m, 64));
      if (lcol == 0)
        atomicMin(rowmin + b * N_ + n0 + wave * 64 + i * 16 + quad * 4 + r,
                  __float_as_uint(v));
    }

  __syncthreads();
  // colmin: flush LDS table to global
#pragma unroll
  for (int i = 0; i < 2; ++i) {
    int idx = t + i * 256;
    atomicMin(colmin + b * N_ + m0 + idx, cmin_s[idx]);
  }
#undef STAGE_B
}

// 64 blocks x 256 threads: 16384 uint4 = 65536 mins; wave-reduce + atomicAdd.
__global__ __launch_bounds__(256) void reduce_kernel(
    const unsigned* __restrict__ mins,   // rowmin then colmin, contiguous
    float* __restrict__ out)
{
  int idx = blockIdx.x * 256 + threadIdx.x;
  uint4 u = ((const uint4*)mins)[idx];
  float s = __uint_as_float(u.x) + __uint_as_float(u.y)
          + __uint_as_float(u.z) + __uint_as_float(u.w);
#pragma unroll
  for (int m = 1; m < 64; m <<= 1) s += __shfl_xor(s, m, 64);
  if ((threadIdx.x & 63) == 0) atomicAdd(out, s);
}

extern "C" void kernel_launch(void* const* d_in, const int* in_sizes, int n_in,
                              void* d_out, int out_size, void* d_ws, size_t ws_size,
                              hipStream_t stream) {
  const float* gts   = (const float*)d_in[0];   // [8,4096,256] fp32
  const float* preds = (const float*)d_in[1];   // [8,4096,256] fp32

  char* ws = (char*)d_ws;
  const size_t XB_BYTES = (size_t)B_ * N_ * D_;         // 8 MiB each (fp8)
  unsigned char* Xf     = (unsigned char*)ws;
  unsigned char* Yf     = (unsigned char*)(ws + XB_BYTES);
  float*    xx     = (float*)(ws + 2 * XB_BYTES);
  float*    yy     = (float*)(ws + 2 * XB_BYTES + (size_t)B_ * N_ * 4);
  unsigned* rowmin = (unsigned*)(ws + 2 * XB_BYTES + (size_t)B_ * N_ * 8);
  unsigned* colmin = (unsigned*)(ws + 2 * XB_BYTES + (size_t)B_ * N_ * 12);

  // 4096 row-groups of 16 (X then Y), one wave each -> 1024 blocks
  prep_kernel<<<1024, 256, 0, stream>>>(gts, preds, Xf, Yf, xx, yy, rowmin, colmin,
                                        (float*)d_out);

  // 8 batches x 16 row-tiles(256) x 8 col-eighths(512) = 1024 blocks = 4/CU
  chamfer_gemm<<<1024, 256, 0, stream>>>(Xf, Yf, xx, yy, rowmin, colmin);

  reduce_kernel<<<64, 256, 0, stream>>>(rowmin, (float*)d_out);
}

// Round 9
// 141.352 us; speedup vs baseline: 1.9781x; 1.9781x over previous
//
#include <hip/hip_runtime.h>

typedef int   i32x8 __attribute__((ext_vector_type(8)));
typedef float f32x4 __attribute__((ext_vector_type(4)));

#define B_   8
#define N_   4096
#define D_   256

// fp8 fragment-major blob layout:
//   blob[g16][kt][h] = 1 KB chunk; lane l's 16 bytes at +l*16 hold
//   P[g16*16 + (l&15)][k = kt*128 + (l>>4)*32 + h*16 .. +16]  (e4m3)

__device__ __forceinline__ void gl_lds16(const void* g, void* l) {
  __builtin_amdgcn_global_load_lds(
      (const __attribute__((address_space(1))) unsigned int*)g,
      (__attribute__((address_space(3))) unsigned int*)l, 16, 0, 0);
}

// sum of squares of the 4 e4m3 bytes in w (selector must be a literal)
__device__ __forceinline__ float sq8(unsigned w) {
  float f0 = __builtin_amdgcn_cvt_f32_fp8(w, 0);
  float f1 = __builtin_amdgcn_cvt_f32_fp8(w, 1);
  float f2 = __builtin_amdgcn_cvt_f32_fp8(w, 2);
  float f3 = __builtin_amdgcn_cvt_f32_fp8(w, 3);
  return f0 * f0 + f1 * f1 + f2 * f2 + f3 * f3;
}

// One wave per 16-row group: fp32 -> fp8 e4m3 convert (coalesced 1 KB float4
// reads), in-wave LDS transpose to fragment-major, norms of DEQUANTIZED
// values accumulated during readback, min-init.
__global__ __launch_bounds__(256) void prep_kernel(
    const float* __restrict__ x, const float* __restrict__ y,
    unsigned char* __restrict__ Xf, unsigned char* __restrict__ Yf,
    float* __restrict__ xx, float* __restrict__ yy,
    unsigned* __restrict__ rowmin, unsigned* __restrict__ colmin,
    float* __restrict__ out)
{
  __shared__ unsigned char T[4][16 * 272];   // 16 rows x 256B fp8 (+16 pad)
  if (blockIdx.x == 0 && threadIdx.x == 0) out[0] = 0.f;

  const int wv = threadIdx.x >> 6, lane = threadIdx.x & 63;
  const int wid = (blockIdx.x << 2) + wv;          // 0..4095

  const float* src; unsigned char* dst; float* nrm; unsigned* mn; int g;
  if (wid < 2048) { g = wid;        src = x; dst = Xf; nrm = xx; mn = rowmin; }
  else            { g = wid - 2048; src = y; dst = Yf; nrm = yy; mn = colmin; }

  unsigned char* tw = T[wv];
  const float* rp = src + (size_t)g * 16 * D_;
#pragma unroll
  for (int r = 0; r < 16; ++r) {
    float4 v = *(const float4*)(rp + r * D_ + lane * 4);   // 1 KB contiguous
    unsigned u = __builtin_amdgcn_cvt_pk_fp8_f32(v.x, v.y, 0, 0);
    u = __builtin_amdgcn_cvt_pk_fp8_f32(v.z, v.w, u, 1);   // bytes = x,y,z,w
    *(unsigned*)(tw + r * 272 + lane * 4) = u;
  }
  __syncthreads();

  // fragment-order readback: row = lane&15, k-base = (lane>>4)*32
  float s = 0.f;
  const int row = lane & 15, ko = (lane >> 4) * 32;
#pragma unroll
  for (int kt = 0; kt < 2; ++kt)
#pragma unroll
    for (int h = 0; h < 2; ++h) {
      uint4 c = *(const uint4*)(tw + row * 272 + kt * 128 + ko + h * 16);
      s += sq8(c.x) + sq8(c.y) + sq8(c.z) + sq8(c.w);
      *(uint4*)(dst + ((((size_t)g * 2 + kt) * 2 + h) << 10) + lane * 16) = c;
    }
  s += __shfl_xor(s, 16, 64);   // fold quads: row (lane&15)'s full norm
  s += __shfl_xor(s, 32, 64);
  if      (lane < 16) nrm[g * 16 + lane] = s;
  else if (lane < 32) mn[g * 16 + lane - 16] = 0x7f800000u;   // +inf
}

// MX-fp8 chamfer GEMM (mfma_scale_f32_16x16x128_f8f6f4, scales = 1.0).
// Block: 128 rows x 1024 cols; 4 waves x 32 rows; af[2][2] (32 VGPRs) in
// regs -> total reg demand ~100 fits the 128/lane cap of (256,4) WITHOUT
// spilling (round-8 lesson: af[4][2]=64 regs + bound(256,4) => scratch
// spill, FETCH 588 MB). Grid 1024 = exactly 4 blocks/CU.
__global__ __launch_bounds__(256, 4) void chamfer_gemm(
    const unsigned char* __restrict__ Xf, const unsigned char* __restrict__ Yf,
    const float* __restrict__ xx, const float* __restrict__ yy,
    unsigned* __restrict__ rowmin, unsigned* __restrict__ colmin)
{
  __shared__ __align__(16) unsigned char S[2][8192];   // B double-buffer
  __shared__ unsigned cmin_s[1024];                    // col-min table

  const int bid = blockIdx.x;
  const int b   = bid & 7;                   // batch == XCD (L2 locality)
  const int rt  = (bid >> 3) & 31;           // 32 row-tiles of 128
  const int cq  = bid >> 8;                  // 0..3 col-quarters of 1024
  const int n0  = rt * 128;
  const int m0  = cq * 1024;

  const int t = threadIdx.x, lane = t & 63, wave = t >> 6;
  const int quad = lane >> 4, lcol = lane & 15;

#pragma unroll
  for (int i = 0; i < 4; ++i) cmin_s[t + i * 256] = 0x7f800000u;

  // ---- A fragments -> registers (coalesced dwordx4 from fragment blob) ----
  i32x8 af[2][2];
#pragma unroll
  for (int i = 0; i < 2; ++i) {
    const size_t g = (size_t)(b * 256 + rt * 8 + wave * 2 + i);
#pragma unroll
    for (int kt = 0; kt < 2; ++kt) {
      const uint4* p = (const uint4*)(Xf + ((g * 2 + kt) << 11));
      uint4 lo = p[lane];        // h=0
      uint4 hi = p[64 + lane];   // h=1
      i32x8 a;
      a[0] = lo.x; a[1] = lo.y; a[2] = lo.z; a[3] = lo.w;
      a[4] = hi.x; a[5] = hi.y; a[6] = hi.z; a[7] = hi.w;
      af[i][kt] = a;
    }
  }

  float xv[2][4], rmin[2][4];
  const float* xxp = xx + b * N_ + n0 + wave * 32;
#pragma unroll
  for (int i = 0; i < 2; ++i)
#pragma unroll
    for (int r = 0; r < 4; ++r) {
      xv[i][r] = xxp[i * 16 + quad * 4 + r];
      rmin[i][r] = 1e30f;
    }

  __syncthreads();   // cmin_s init visible

  // B staging (identical to round 7): LDS chunk cd = kt*4 + h*2 + j at
  // cd*1024; slot s = t + h2*256 -> cd = s>>6 (wave-uniform), lane = s&63.
  const unsigned char* Ybase = Yf + ((size_t)(b * 256 + cq * 64) << 12);
  const float* yyp = yy + b * N_ + m0;

#define STAGE_B(ct_, buf_)                                                    \
  {                                                                           \
    const unsigned char* Ysrc = Ybase + ((size_t)(ct_) << 13);  /* 2 g16 */   \
    _Pragma("unroll")                                                         \
    for (int h2 = 0; h2 < 2; ++h2) {                                          \
      int s  = t + h2 * 256;                                                  \
      int cd = s >> 6, ln = s & 63;                                           \
      int kt = cd >> 2, hh = (cd >> 1) & 1, jj = cd & 1;                      \
      gl_lds16(Ysrc + jj * 4096 + kt * 2048 + hh * 1024 + ln * 16,            \
               (buf_) + s * 16);                                              \
    }                                                                         \
  }

  STAGE_B(0, S[0]);   // prefetch first tile

  for (int ct = 0; ct < 32; ++ct) {
    __syncthreads();                       // drains B(ct) prefetch
    const unsigned char* curb = S[ct & 1];
    if (ct + 1 < 32) STAGE_B(ct + 1, S[(ct + 1) & 1]);

    float yv0 = yyp[ct * 32 + lcol];
    float yv1 = yyp[ct * 32 + 16 + lcol];

    // B fragments: bq[j][kt] from chunks (kt, h, j)
    i32x8 bq[2][2];
#pragma unroll
    for (int j = 0; j < 2; ++j)
#pragma unroll
      for (int kt = 0; kt < 2; ++kt) {
        uint4 lo = *(const uint4*)(curb + (kt * 4 + 0 + j) * 1024 + lane * 16);
        uint4 hi = *(const uint4*)(curb + (kt * 4 + 2 + j) * 1024 + lane * 16);
        i32x8 v;
        v[0] = lo.x; v[1] = lo.y; v[2] = lo.z; v[3] = lo.w;
        v[4] = hi.x; v[5] = hi.y; v[6] = hi.z; v[7] = hi.w;
        bq[j][kt] = v;
      }

    f32x4 acc[2][2] = {};
#pragma unroll
    for (int kt = 0; kt < 2; ++kt)
#pragma unroll
      for (int i = 0; i < 2; ++i)
#pragma unroll
        for (int j = 0; j < 2; ++j)
          acc[i][j] = __builtin_amdgcn_mfma_scale_f32_16x16x128_f8f6f4(
              af[i][kt], bq[j][kt], acc[i][j],
              0, 0,        // cbsz = A fmt e4m3, blgp = B fmt e4m3
              0, 127,      // scale A: opsel 0, e8m0 127 = 1.0
              0, 127);     // scale B

    // ---- epilogue: C/D row = i*16 + quad*4 + r, col = j*16 + lcol ----
#pragma unroll
    for (int j = 0; j < 2; ++j) {
      float yv = j ? yv1 : yv0;
      float cm = 1e30f;
#pragma unroll
      for (int i = 0; i < 2; ++i)
#pragma unroll
        for (int r = 0; r < 4; ++r) {
          float a = acc[i][j][r];
          rmin[i][r] = fminf(rmin[i][r], __builtin_fmaf(-2.0f, a, yv));
          cm         = fminf(cm,         __builtin_fmaf(-2.0f, a, xv[i][r]));
        }
      cm = fminf(cm, __shfl_xor(cm, 16, 64));
      cm = fminf(cm, __shfl_xor(cm, 32, 64));
      if (quad == 0)
        atomicMin(&cmin_s[ct * 32 + j * 16 + lcol], __float_as_uint(cm + yv));
    }
  }

  // rowmin: one global atomic set per block (32 rows/wave)
#pragma unroll
  for (int i = 0; i < 2; ++i)
#pragma unroll
    for (int r = 0; r < 4; ++r) {
      float v = xv[i][r] + rmin[i][r];
#pragma unroll
      for (int m = 1; m < 16; m <<= 1) v = fminf(v, __shfl_xor(v, m, 64));
      if (lcol == 0)
        atomicMin(rowmin + b * N_ + n0 + wave * 32 + i * 16 + quad * 4 + r,
                  __float_as_uint(v));
    }

  __syncthreads();
  // colmin: flush LDS table to global
#pragma unroll
  for (int i = 0; i < 4; ++i) {
    int idx = t + i * 256;
    atomicMin(colmin + b * N_ + m0 + idx, cmin_s[idx]);
  }
#undef STAGE_B
}

// 64 blocks x 256 threads: 16384 uint4 = 65536 mins; wave-reduce + atomicAdd.
__global__ __launch_bounds__(256) void reduce_kernel(
    const unsigned* __restrict__ mins,   // rowmin then colmin, contiguous
    float* __restrict__ out)
{
  int idx = blockIdx.x * 256 + threadIdx.x;
  uint4 u = ((const uint4*)mins)[idx];
  float s = __uint_as_float(u.x) + __uint_as_float(u.y)
          + __uint_as_float(u.z) + __uint_as_float(u.w);
#pragma unroll
  for (int m = 1; m < 64; m <<= 1) s += __shfl_xor(s, m, 64);
  if ((threadIdx.x & 63) == 0) atomicAdd(out, s);
}

extern "C" void kernel_launch(void* const* d_in, const int* in_sizes, int n_in,
                              void* d_out, int out_size, void* d_ws, size_t ws_size,
                              hipStream_t stream) {
  const float* gts   = (const float*)d_in[0];   // [8,4096,256] fp32
  const float* preds = (const float*)d_in[1];   // [8,4096,256] fp32

  char* ws = (char*)d_ws;
  const size_t XB_BYTES = (size_t)B_ * N_ * D_;         // 8 MiB each (fp8)
  unsigned char* Xf     = (unsigned char*)ws;
  unsigned char* Yf     = (unsigned char*)(ws + XB_BYTES);
  float*    xx     = (float*)(ws + 2 * XB_BYTES);
  float*    yy     = (float*)(ws + 2 * XB_BYTES + (size_t)B_ * N_ * 4);
  unsigned* rowmin = (unsigned*)(ws + 2 * XB_BYTES + (size_t)B_ * N_ * 8);
  unsigned* colmin = (unsigned*)(ws + 2 * XB_BYTES + (size_t)B_ * N_ * 12);

  // 4096 row-groups of 16 (X then Y), one wave each -> 1024 blocks
  prep_kernel<<<1024, 256, 0, stream>>>(gts, preds, Xf, Yf, xx, yy, rowmin, colmin,
                                        (float*)d_out);

  // 8 batches x 32 row-tiles(128) x 4 col-quarters(1024) = 1024 blocks = 4/CU
  chamfer_gemm<<<1024, 256, 0, stream>>>(Xf, Yf, xx, yy, rowmin, colmin);

  reduce_kernel<<<64, 256, 0, stream>>>(rowmin, (float*)d_out);
}

// Round 10
// 139.346 us; speedup vs baseline: 2.0065x; 1.0144x over previous
//
#include <hip/hip_runtime.h>

typedef int   i32x8 __attribute__((ext_vector_type(8)));
typedef float f32x4 __attribute__((ext_vector_type(4)));

#define B_   8
#define N_   4096
#define D_   256

// fp8 fragment-major blob layout:
//   blob[g16][kt][h] = 1 KB chunk; lane l's 16 bytes at +l*16 hold
//   P[g16*16 + (l&15)][k = kt*128 + (l>>4)*32 + h*16 .. +16]  (e4m3)

__device__ __forceinline__ void gl_lds16(const void* g, void* l) {
  __builtin_amdgcn_global_load_lds(
      (const __attribute__((address_space(1))) unsigned int*)g,
      (__attribute__((address_space(3))) unsigned int*)l, 16, 0, 0);
}

// sum of squares of the 4 e4m3 bytes in w (selector must be a literal)
__device__ __forceinline__ float sq8(unsigned w) {
  float f0 = __builtin_amdgcn_cvt_f32_fp8(w, 0);
  float f1 = __builtin_amdgcn_cvt_f32_fp8(w, 1);
  float f2 = __builtin_amdgcn_cvt_f32_fp8(w, 2);
  float f3 = __builtin_amdgcn_cvt_f32_fp8(w, 3);
  return f0 * f0 + f1 * f1 + f2 * f2 + f3 * f3;
}

// One wave per 16-row group: fp32 -> fp8 e4m3 convert (coalesced 1 KB float4
// reads), in-wave LDS transpose to fragment-major, norms of DEQUANTIZED
// values accumulated during readback, min-init.
__global__ __launch_bounds__(256) void prep_kernel(
    const float* __restrict__ x, const float* __restrict__ y,
    unsigned char* __restrict__ Xf, unsigned char* __restrict__ Yf,
    float* __restrict__ xx, float* __restrict__ yy,
    unsigned* __restrict__ rowmin, unsigned* __restrict__ colmin,
    float* __restrict__ out)
{
  __shared__ unsigned char T[4][16 * 272];   // 16 rows x 256B fp8 (+16 pad)
  if (blockIdx.x == 0 && threadIdx.x == 0) out[0] = 0.f;

  const int wv = threadIdx.x >> 6, lane = threadIdx.x & 63;
  const int wid = (blockIdx.x << 2) + wv;          // 0..4095

  const float* src; unsigned char* dst; float* nrm; unsigned* mn; int g;
  if (wid < 2048) { g = wid;        src = x; dst = Xf; nrm = xx; mn = rowmin; }
  else            { g = wid - 2048; src = y; dst = Yf; nrm = yy; mn = colmin; }

  unsigned char* tw = T[wv];
  const float* rp = src + (size_t)g * 16 * D_;
#pragma unroll
  for (int r = 0; r < 16; ++r) {
    float4 v = *(const float4*)(rp + r * D_ + lane * 4);   // 1 KB contiguous
    unsigned u = __builtin_amdgcn_cvt_pk_fp8_f32(v.x, v.y, 0, 0);
    u = __builtin_amdgcn_cvt_pk_fp8_f32(v.z, v.w, u, 1);   // bytes = x,y,z,w
    *(unsigned*)(tw + r * 272 + lane * 4) = u;
  }
  __syncthreads();

  // fragment-order readback: row = lane&15, k-base = (lane>>4)*32
  float s = 0.f;
  const int row = lane & 15, ko = (lane >> 4) * 32;
#pragma unroll
  for (int kt = 0; kt < 2; ++kt)
#pragma unroll
    for (int h = 0; h < 2; ++h) {
      uint4 c = *(const uint4*)(tw + row * 272 + kt * 128 + ko + h * 16);
      s += sq8(c.x) + sq8(c.y) + sq8(c.z) + sq8(c.w);
      *(uint4*)(dst + ((((size_t)g * 2 + kt) * 2 + h) << 10) + lane * 16) = c;
    }
  s += __shfl_xor(s, 16, 64);   // fold quads: row (lane&15)'s full norm
  s += __shfl_xor(s, 32, 64);
  if      (lane < 16) nrm[g * 16 + lane] = s;
  else if (lane < 32) mn[g * 16 + lane - 16] = 0x7f800000u;   // +inf
}

// MX-fp8 chamfer GEMM (mfma_scale_f32_16x16x128_f8f6f4, scales = 1.0).
// Block: 128 rows x 1024 cols; 4 waves x 32 rows; af[2][2] in regs.
// Round-10: 2 col-tiles per barrier, 4-buffer rotation (36 KB LDS, still
// 4 blocks/CU). Between barriers each wave has 2 independent ct of work
// (bq reads of ct2 overlap ct1's epilogue; waves drift out of phase), and
// barrier count halves 32->16 -- attacks the round-9 pipe convoy.
__global__ __launch_bounds__(256, 4) void chamfer_gemm(
    const unsigned char* __restrict__ Xf, const unsigned char* __restrict__ Yf,
    const float* __restrict__ xx, const float* __restrict__ yy,
    unsigned* __restrict__ rowmin, unsigned* __restrict__ colmin)
{
  __shared__ __align__(16) unsigned char S[4][8192];   // 4-tile rotation
  __shared__ unsigned cmin_s[1024];                    // col-min table

  const int bid = blockIdx.x;
  const int b   = bid & 7;                   // batch == XCD (L2 locality)
  const int rt  = (bid >> 3) & 31;           // 32 row-tiles of 128
  const int cq  = bid >> 8;                  // 0..3 col-quarters of 1024
  const int n0  = rt * 128;
  const int m0  = cq * 1024;

  const int t = threadIdx.x, lane = t & 63, wave = t >> 6;
  const int quad = lane >> 4, lcol = lane & 15;

#pragma unroll
  for (int i = 0; i < 4; ++i) cmin_s[t + i * 256] = 0x7f800000u;

  // ---- A fragments -> registers (coalesced dwordx4 from fragment blob) ----
  i32x8 af[2][2];
#pragma unroll
  for (int i = 0; i < 2; ++i) {
    const size_t g = (size_t)(b * 256 + rt * 8 + wave * 2 + i);
#pragma unroll
    for (int kt = 0; kt < 2; ++kt) {
      const uint4* p = (const uint4*)(Xf + ((g * 2 + kt) << 11));
      uint4 lo = p[lane];        // h=0
      uint4 hi = p[64 + lane];   // h=1
      i32x8 a;
      a[0] = lo.x; a[1] = lo.y; a[2] = lo.z; a[3] = lo.w;
      a[4] = hi.x; a[5] = hi.y; a[6] = hi.z; a[7] = hi.w;
      af[i][kt] = a;
    }
  }

  float xv[2][4], rmin[2][4];
  const float* xxp = xx + b * N_ + n0 + wave * 32;
#pragma unroll
  for (int i = 0; i < 2; ++i)
#pragma unroll
    for (int r = 0; r < 4; ++r) {
      xv[i][r] = xxp[i * 16 + quad * 4 + r];
      rmin[i][r] = 1e30f;
    }

  // B staging: LDS chunk cd = kt*4 + h*2 + j at cd*1024; slot s = t + h2*256
  // -> cd = s>>6 (wave-uniform), lane slot = s&63. Source chunk is a
  // contiguous 1 KB of the fragment blob -> perfectly coalesced.
  const unsigned char* Ybase = Yf + ((size_t)(b * 256 + cq * 64) << 12);
  const float* yyp = yy + b * N_ + m0;

#define STAGE_B(ct_, buf_)                                                    \
  {                                                                           \
    const unsigned char* Ysrc = Ybase + ((size_t)(ct_) << 13);  /* 2 g16 */   \
    _Pragma("unroll")                                                         \
    for (int h2 = 0; h2 < 2; ++h2) {                                          \
      int s  = t + h2 * 256;                                                  \
      int cd = s >> 6, ln = s & 63;                                           \
      int kt = cd >> 2, hh = (cd >> 1) & 1, jj = cd & 1;                      \
      gl_lds16(Ysrc + jj * 4096 + kt * 2048 + hh * 1024 + ln * 16,            \
               (buf_) + s * 16);                                              \
    }                                                                         \
  }

  auto do_ct = [&](int ct, const unsigned char* curb) {
    float yv0 = yyp[ct * 32 + lcol];
    float yv1 = yyp[ct * 32 + 16 + lcol];

    // B fragments: bq[j][kt] from chunks (kt, h, j)
    i32x8 bq[2][2];
#pragma unroll
    for (int j = 0; j < 2; ++j)
#pragma unroll
      for (int kt = 0; kt < 2; ++kt) {
        uint4 lo = *(const uint4*)(curb + (kt * 4 + 0 + j) * 1024 + lane * 16);
        uint4 hi = *(const uint4*)(curb + (kt * 4 + 2 + j) * 1024 + lane * 16);
        i32x8 v;
        v[0] = lo.x; v[1] = lo.y; v[2] = lo.z; v[3] = lo.w;
        v[4] = hi.x; v[5] = hi.y; v[6] = hi.z; v[7] = hi.w;
        bq[j][kt] = v;
      }

    f32x4 acc[2][2] = {};
#pragma unroll
    for (int kt = 0; kt < 2; ++kt)
#pragma unroll
      for (int i = 0; i < 2; ++i)
#pragma unroll
        for (int j = 0; j < 2; ++j)
          acc[i][j] = __builtin_amdgcn_mfma_scale_f32_16x16x128_f8f6f4(
              af[i][kt], bq[j][kt], acc[i][j],
              0, 0,        // cbsz = A fmt e4m3, blgp = B fmt e4m3
              0, 127,      // scale A: opsel 0, e8m0 127 = 1.0
              0, 127);     // scale B

    // epilogue: C/D row = i*16 + quad*4 + r, col = j*16 + lcol
#pragma unroll
    for (int j = 0; j < 2; ++j) {
      float yv = j ? yv1 : yv0;
      float cm = 1e30f;
#pragma unroll
      for (int i = 0; i < 2; ++i)
#pragma unroll
        for (int r = 0; r < 4; ++r) {
          float a = acc[i][j][r];
          rmin[i][r] = fminf(rmin[i][r], __builtin_fmaf(-2.0f, a, yv));
          cm         = fminf(cm,         __builtin_fmaf(-2.0f, a, xv[i][r]));
        }
      cm = fminf(cm, __shfl_xor(cm, 16, 64));
      cm = fminf(cm, __shfl_xor(cm, 32, 64));
      if (quad == 0)
        atomicMin(&cmin_s[ct * 32 + j * 16 + lcol], __float_as_uint(cm + yv));
    }
  };

  // prologue: stage group 0 (tiles 0,1) into bufs 0,1
  STAGE_B(0, S[0]);
  STAGE_B(1, S[1]);

  for (int g = 0; g < 16; ++g) {
    __syncthreads();   // drains group-g staging; group g-1 bufs now free
    const int cur = (g & 1) * 2;
    if (g + 1 < 16) {
      const int nxt = ((g + 1) & 1) * 2;
      STAGE_B(2 * g + 2, S[nxt]);       // in flight across this whole group
      STAGE_B(2 * g + 3, S[nxt + 1]);
    }
    do_ct(2 * g,     S[cur]);           // no barrier between these two:
    do_ct(2 * g + 1, S[cur + 1]);       // ct2 bq reads overlap ct1 epilogue
  }

  // rowmin: one global atomic set per block (32 rows/wave)
#pragma unroll
  for (int i = 0; i < 2; ++i)
#pragma unroll
    for (int r = 0; r < 4; ++r) {
      float v = xv[i][r] + rmin[i][r];
#pragma unroll
      for (int m = 1; m < 16; m <<= 1) v = fminf(v, __shfl_xor(v, m, 64));
      if (lcol == 0)
        atomicMin(rowmin + b * N_ + n0 + wave * 32 + i * 16 + quad * 4 + r,
                  __float_as_uint(v));
    }

  __syncthreads();
  // colmin: flush LDS table to global
#pragma unroll
  for (int i = 0; i < 4; ++i) {
    int idx = t + i * 256;
    atomicMin(colmin + b * N_ + m0 + idx, cmin_s[idx]);
  }
#undef STAGE_B
}

// 64 blocks x 256 threads: 16384 uint4 = 65536 mins; wave-reduce + atomicAdd.
__global__ __launch_bounds__(256) void reduce_kernel(
    const unsigned* __restrict__ mins,   // rowmin then colmin, contiguous
    float* __restrict__ out)
{
  int idx = blockIdx.x * 256 + threadIdx.x;
  uint4 u = ((const uint4*)mins)[idx];
  float s = __uint_as_float(u.x) + __uint_as_float(u.y)
          + __uint_as_float(u.z) + __uint_as_float(u.w);
#pragma unroll
  for (int m = 1; m < 64; m <<= 1) s += __shfl_xor(s, m, 64);
  if ((threadIdx.x & 63) == 0) atomicAdd(out, s);
}

extern "C" void kernel_launch(void* const* d_in, const int* in_sizes, int n_in,
                              void* d_out, int out_size, void* d_ws, size_t ws_size,
                              hipStream_t stream) {
  const float* gts   = (const float*)d_in[0];   // [8,4096,256] fp32
  const float* preds = (const float*)d_in[1];   // [8,4096,256] fp32

  char* ws = (char*)d_ws;
  const size_t XB_BYTES = (size_t)B_ * N_ * D_;         // 8 MiB each (fp8)
  unsigned char* Xf     = (unsigned char*)ws;
  unsigned char* Yf     = (unsigned char*)(ws + XB_BYTES);
  float*    xx     = (float*)(ws + 2 * XB_BYTES);
  float*    yy     = (float*)(ws + 2 * XB_BYTES + (size_t)B_ * N_ * 4);
  unsigned* rowmin = (unsigned*)(ws + 2 * XB_BYTES + (size_t)B_ * N_ * 8);
  unsigned* colmin = (unsigned*)(ws + 2 * XB_BYTES + (size_t)B_ * N_ * 12);

  // 4096 row-groups of 16 (X then Y), one wave each -> 1024 blocks
  prep_kernel<<<1024, 256, 0, stream>>>(gts, preds, Xf, Yf, xx, yy, rowmin, colmin,
                                        (float*)d_out);

  // 8 batches x 32 row-tiles(128) x 4 col-quarters(1024) = 1024 blocks = 4/CU
  chamfer_gemm<<<1024, 256, 0, stream>>>(Xf, Yf, xx, yy, rowmin, colmin);

  reduce_kernel<<<64, 256, 0, stream>>>(rowmin, (float*)d_out);
}